// Round 5
// baseline (2963.715 us; speedup 1.0000x reference)
//
#include <hip/hip_runtime.h>
#include <math.h>

#ifndef M_PI
#define M_PI 3.14159265358979323846
#endif

#define NLVL 16
#define TSZ 524288u
#define TMSK (TSZ - 1u)
#define PRIME1 2654435761u
#define PRIME2 805459861u

struct ResList { float r[NLVL]; };

__device__ __forceinline__ float relu_act(float x) { return fmaxf(x, 0.0f); }
__device__ __forceinline__ float sigmoid_act(float x) { return 1.0f / (1.0f + expf(-x)); }

// Dense layer, fully unrolled. W/B pointers are uniform kernel args and all
// offsets are compile-time constants -> scalar (s_load) weight traffic.
// ACT: 0 = relu, 1 = sigmoid
template<int IN, int OUT, int ACT>
__device__ __forceinline__ void dense(const float* __restrict__ W,
                                      const float* __restrict__ Bv,
                                      const float (&in)[IN], float (&out)[OUT]) {
    #pragma unroll
    for (int o = 0; o < OUT; ++o) {
        float acc = Bv[o];
        const float4* wr = reinterpret_cast<const float4*>(W + o * IN);
        #pragma unroll
        for (int i = 0; i < IN / 4; ++i) {
            float4 w = wr[i];
            acc = fmaf(w.x, in[4*i+0], acc);
            acc = fmaf(w.y, in[4*i+1], acc);
            acc = fmaf(w.z, in[4*i+2], acc);
            acc = fmaf(w.w, in[4*i+3], acc);
        }
        out[o] = (ACT == 0) ? relu_act(acc) : sigmoid_act(acc);
    }
}

__global__ void dir_encode_kernel(const float* __restrict__ D, float* __restrict__ De, int R) {
    int r = blockIdx.x * blockDim.x + threadIdx.x;
    if (r >= R) return;
    float d0 = D[3*r+0], d1 = D[3*r+1], d2 = D[3*r+2];
    float* o = De + 24 * r;
    #pragma unroll
    for (int i = 0; i < 4; ++i) {
        float s = (float)((double)(1 << i) * M_PI);  // rounded to f32 like jnp
        o[6*i+0] = sinf(s * d0);
        o[6*i+1] = sinf(s * d1);
        o[6*i+2] = sinf(s * d2);
        o[6*i+3] = cosf(s * d0);
        o[6*i+4] = cosf(s * d1);
        o[6*i+5] = cosf(s * d2);
    }
}

template<bool USE_WS>
__global__ __launch_bounds__(256)
void ngp_fused(const float* __restrict__ X,
               const float* __restrict__ D,
               const float* __restrict__ tables,
               const float* __restrict__ w1, const float* __restrict__ b1,
               const float* __restrict__ w2, const float* __restrict__ b2,
               const float* __restrict__ cw1, const float* __restrict__ cb1,
               const float* __restrict__ cw2, const float* __restrict__ cb2,
               const float* __restrict__ cw3, const float* __restrict__ cb3,
               const float* __restrict__ De,
               float* __restrict__ out, int N, int R, int rmask, ResList res) {
    int n = blockIdx.x * blockDim.x + threadIdx.x;
    if (n >= N) return;
    float x = X[3*n+0], y = X[3*n+1], z = X[3*n+2];

    // ---- multiresolution hash encoding (16 levels x 2 features) ----
    float xe[32];
    #pragma unroll
    for (int l = 0; l < NLVL; ++l) {
        float rs = res.r[l];
        float sx = x * rs, sy = y * rs, sz = z * rs;
        float px = floorf(sx), py = floorf(sy), pz = floorf(sz);
        float fx = sx - px, fy = sy - py, fz = sz - pz;
        unsigned cx = (unsigned)(int)px;
        unsigned cy = (unsigned)(int)py;
        unsigned cz = (unsigned)(int)pz;
        unsigned hx[2] = { cx,          cx + 1u };
        unsigned hy[2] = { cy * PRIME1, cy * PRIME1 + PRIME1 };
        unsigned hz[2] = { cz * PRIME2, cz * PRIME2 + PRIME2 };
        float wxv[2] = { 1.0f - fx, fx };
        float wyv[2] = { 1.0f - fy, fy };
        float wzv[2] = { 1.0f - fz, fz };
        const float2* tl = reinterpret_cast<const float2*>(tables) + (size_t)l * TSZ;
        float f0 = 0.0f, f1 = 0.0f;
        #pragma unroll
        for (int i = 0; i < 2; ++i)
            #pragma unroll
            for (int j = 0; j < 2; ++j)
                #pragma unroll
                for (int k = 0; k < 2; ++k) {
                    unsigned idx = (hx[i] ^ hy[j] ^ hz[k]) & TMSK;
                    float2 f = tl[idx];
                    float w = wxv[i] * wyv[j] * wzv[k];
                    f0 = fmaf(w, f.x, f0);
                    f1 = fmaf(w, f.y, f1);
                }
        xe[2*l+0] = f0;
        xe[2*l+1] = f1;
    }

    // ---- density MLP: 32 -> 64 (relu) -> 16 (sigmoid) ----
    float h[64];
    dense<32, 64, 0>(w1, b1, xe, h);
    float cin[40];
    {
        float dens[16];
        dense<64, 16, 1>(w2, b2, h, dens);
        #pragma unroll
        for (int i = 0; i < 16; ++i) cin[i] = dens[i];
    }
    float dens0 = cin[0];  // density[:,0] output — keep a copy for liveness

    // ---- direction encoding features (24) ----
    int ray = rmask ? (n & rmask) : (n % R);
    if (USE_WS) {
        const float4* der = reinterpret_cast<const float4*>(De + 24 * ray);
        #pragma unroll
        for (int i = 0; i < 6; ++i) {
            float4 v = der[i];
            cin[16 + 4*i + 0] = v.x;
            cin[16 + 4*i + 1] = v.y;
            cin[16 + 4*i + 2] = v.z;
            cin[16 + 4*i + 3] = v.w;
        }
    } else {
        float d0 = D[3*ray+0], d1 = D[3*ray+1], d2 = D[3*ray+2];
        #pragma unroll
        for (int i = 0; i < 4; ++i) {
            float s = (float)((double)(1 << i) * M_PI);
            cin[16 + 6*i + 0] = sinf(s * d0);
            cin[16 + 6*i + 1] = sinf(s * d1);
            cin[16 + 6*i + 2] = sinf(s * d2);
            cin[16 + 6*i + 3] = cosf(s * d0);
            cin[16 + 6*i + 4] = cosf(s * d1);
            cin[16 + 6*i + 5] = cosf(s * d2);
        }
    }

    // ---- colour MLP: 40 -> 64 (relu) -> [64 (relu) -> 3 (sigmoid)] fused ----
    float c1[64];
    dense<40, 64, 0>(cw1, cb1, cin, c1);

    // Fuse the 64->64 relu layer with the 64->3 head: each c2[o] is consumed
    // immediately by the 3 colour accumulators, so c2 is never materialized.
    // Peak live registers drop from ~128 floats (c1+c2) to ~70 (c1+3 accs).
    float ca0 = cb3[0], ca1 = cb3[1], ca2 = cb3[2];
    #pragma unroll
    for (int o = 0; o < 64; ++o) {
        float acc = cb2[o];
        const float4* wr = reinterpret_cast<const float4*>(cw2 + o * 64);
        #pragma unroll
        for (int i = 0; i < 16; ++i) {
            float4 w = wr[i];
            acc = fmaf(w.x, c1[4*i+0], acc);
            acc = fmaf(w.y, c1[4*i+1], acc);
            acc = fmaf(w.z, c1[4*i+2], acc);
            acc = fmaf(w.w, c1[4*i+3], acc);
        }
        float c2o = fmaxf(acc, 0.0f);
        ca0 = fmaf(cw3[0 * 64 + o], c2o, ca0);
        ca1 = fmaf(cw3[1 * 64 + o], c2o, ca1);
        ca2 = fmaf(cw3[2 * 64 + o], c2o, ca2);
    }

    // ---- outputs: density[:,0] (N floats), then colour (N x 3) ----
    out[n] = dens0;
    float* oc = out + N;
    // write-once, never re-read: nontemporal keeps colour stores out of L2,
    // leaving more L2 for the hash-table gather stream.
    __builtin_nontemporal_store(sigmoid_act(ca0), &oc[3*n+0]);
    __builtin_nontemporal_store(sigmoid_act(ca1), &oc[3*n+1]);
    __builtin_nontemporal_store(sigmoid_act(ca2), &oc[3*n+2]);
}

extern "C" void kernel_launch(void* const* d_in, const int* in_sizes, int n_in,
                              void* d_out, int out_size, void* d_ws, size_t ws_size,
                              hipStream_t stream) {
    const float* X      = (const float*)d_in[0];
    const float* D      = (const float*)d_in[1];
    // d_in[2] is M (device scalar) — not readable without sync; derive from sizes.
    const float* tables = (const float*)d_in[3];
    const float* w1  = (const float*)d_in[4];
    const float* b1  = (const float*)d_in[5];
    const float* w2  = (const float*)d_in[6];
    const float* b2  = (const float*)d_in[7];
    const float* cw1 = (const float*)d_in[8];
    const float* cb1 = (const float*)d_in[9];
    const float* cw2 = (const float*)d_in[10];
    const float* cb2 = (const float*)d_in[11];
    const float* cw3 = (const float*)d_in[12];
    const float* cb3 = (const float*)d_in[13];

    int N = in_sizes[0] / 3;   // 1,048,576 sample points
    int R = in_sizes[1] / 3;   // 32,768 rays
    int rmask = ((R & (R - 1)) == 0) ? (R - 1) : 0;  // pow2 fast path for n % R
    float* out = (float*)d_out;

    // Resolutions: must match numpy's double-precision floor(16 * (32^(1/15))^l)
    // bit-for-bit (511-vs-512 at l=15 would corrupt every hash index).
    ResList res;
    double B = pow(32.0, 1.0 / 15.0);
    for (int l = 0; l < NLVL; ++l) res.r[l] = (float)floor(16.0 * pow(B, (double)l));

    size_t de_bytes = (size_t)R * 24 * sizeof(float);
    int blocks = (N + 255) / 256;
    if (ws_size >= de_bytes) {
        float* De = (float*)d_ws;
        dir_encode_kernel<<<(R + 255) / 256, 256, 0, stream>>>(D, De, R);
        ngp_fused<true><<<blocks, 256, 0, stream>>>(X, D, tables, w1, b1, w2, b2,
            cw1, cb1, cw2, cb2, cw3, cb3, De, out, N, R, rmask, res);
    } else {
        ngp_fused<false><<<blocks, 256, 0, stream>>>(X, D, tables, w1, b1, w2, b2,
            cw1, cb1, cw2, cb2, cw3, cb3, nullptr, out, N, R, rmask, res);
    }
}

// Round 16
// 1197.526 us; speedup vs baseline: 2.4749x; 2.4749x over previous
//
#include <hip/hip_runtime.h>
#include <math.h>
#include <string.h>

#ifndef M_PI
#define M_PI 3.14159265358979323846
#endif

#define NLVL 16
#define TSZ 524288u
#define TMSK (TSZ - 1u)
#define PRIME1 2654435761u
#define PRIME2 805459861u

struct ResList { float r[NLVL]; };

__device__ __forceinline__ float relu_act(float x) { return fmaxf(x, 0.0f); }
__device__ __forceinline__ float sigmoid_act(float x) { return 1.0f / (1.0f + expf(-x)); }

// Dense layer, fully unrolled. W/B pointers are uniform kernel args and all
// offsets are compile-time constants -> scalar-friendly weight traffic.
// ACT: 0 = relu, 1 = sigmoid
template<int IN, int OUT, int ACT>
__device__ __forceinline__ void dense(const float* __restrict__ W,
                                      const float* __restrict__ Bv,
                                      const float (&in)[IN], float (&out)[OUT]) {
    #pragma unroll
    for (int o = 0; o < OUT; ++o) {
        float acc = Bv[o];
        const float4* wr = reinterpret_cast<const float4*>(W + o * IN);
        #pragma unroll
        for (int i = 0; i < IN / 4; ++i) {
            float4 w = wr[i];
            acc = fmaf(w.x, in[4*i+0], acc);
            acc = fmaf(w.y, in[4*i+1], acc);
            acc = fmaf(w.z, in[4*i+2], acc);
            acc = fmaf(w.w, in[4*i+3], acc);
        }
        out[o] = (ACT == 0) ? relu_act(acc) : sigmoid_act(acc);
    }
}

__global__ void dir_encode_kernel(const float* __restrict__ D, float* __restrict__ De, int R) {
    int r = blockIdx.x * blockDim.x + threadIdx.x;
    if (r >= R) return;
    float d0 = D[3*r+0], d1 = D[3*r+1], d2 = D[3*r+2];
    float* o = De + 24 * r;
    #pragma unroll
    for (int i = 0; i < 4; ++i) {
        float s = (float)((double)(1 << i) * M_PI);  // rounded to f32 like jnp
        o[6*i+0] = sinf(s * d0);
        o[6*i+1] = sinf(s * d1);
        o[6*i+2] = sinf(s * d2);
        o[6*i+3] = cosf(s * d0);
        o[6*i+4] = cosf(s * d1);
        o[6*i+5] = cosf(s * d2);
    }
}

// ---------------------------------------------------------------------------
// Pass 1: hash-grid encode, ONE LEVEL PER BLOCK.
//   lvl = blockIdx.x & 15. Since 16 ≡ 0 (mod 8) and wg->XCD assignment is
//   observed round-robin (wgid % 8), every block of level l lands on XCD l%8:
//   each XCD's 4MB L2 serves only 2 tables (<=8MB) instead of all 64MB.
//   (Perf heuristic only — correctness never depends on the mapping.)
// Tiny register footprint -> high occupancy -> many outstanding gathers.
// xe stores are nontemporal so the 128MB stream doesn't evict tables from L2.
// ---------------------------------------------------------------------------
__global__ __launch_bounds__(256)
void hash_encode_kernel(const float* __restrict__ X,
                        const float* __restrict__ tables,
                        unsigned long long* __restrict__ xe_ws,  // float2 as u64
                        int N, ResList res) {
    int w = blockIdx.x;
    int lvl = w & 15;
    int n = (w >> 4) * 256 + (int)threadIdx.x;
    if (n >= N) return;
    float x = X[3*n+0], y = X[3*n+1], z = X[3*n+2];

    float rs = res.r[lvl];
    float sx = x * rs, sy = y * rs, sz = z * rs;
    float px = floorf(sx), py = floorf(sy), pz = floorf(sz);
    float fx = sx - px, fy = sy - py, fz = sz - pz;
    unsigned cx = (unsigned)(int)px;
    unsigned cy = (unsigned)(int)py;
    unsigned cz = (unsigned)(int)pz;
    unsigned hx[2] = { cx,          cx + 1u };
    unsigned hy[2] = { cy * PRIME1, cy * PRIME1 + PRIME1 };
    unsigned hz[2] = { cz * PRIME2, cz * PRIME2 + PRIME2 };
    float wxv[2] = { 1.0f - fx, fx };
    float wyv[2] = { 1.0f - fy, fy };
    float wzv[2] = { 1.0f - fz, fz };
    const float2* tl = reinterpret_cast<const float2*>(tables) + (size_t)lvl * TSZ;
    float f0 = 0.0f, f1 = 0.0f;
    #pragma unroll
    for (int i = 0; i < 2; ++i)
        #pragma unroll
        for (int j = 0; j < 2; ++j)
            #pragma unroll
            for (int k = 0; k < 2; ++k) {
                unsigned idx = (hx[i] ^ hy[j] ^ hz[k]) & TMSK;
                float2 f = tl[idx];
                float wgt = wxv[i] * wyv[j] * wzv[k];
                f0 = fmaf(wgt, f.x, f0);
                f1 = fmaf(wgt, f.y, f1);
            }
    float2 r2; r2.x = f0; r2.y = f1;
    unsigned long long bits;
    memcpy(&bits, &r2, 8);
    __builtin_nontemporal_store(bits, &xe_ws[(size_t)lvl * N + n]);
}

// ---------------------------------------------------------------------------
// Pass 2: pure MLP chain, register-resident, no gathers. VALU-bound; fine at
// 2 waves/SIMD because 64 independent output accumulators give ample ILP.
// ---------------------------------------------------------------------------
__global__ __launch_bounds__(256)
void mlp_kernel(const float2* __restrict__ xe_ws,
                const float* __restrict__ De,
                const float* __restrict__ w1, const float* __restrict__ b1,
                const float* __restrict__ w2, const float* __restrict__ b2,
                const float* __restrict__ cw1, const float* __restrict__ cb1,
                const float* __restrict__ cw2, const float* __restrict__ cb2,
                const float* __restrict__ cw3, const float* __restrict__ cb3,
                float* __restrict__ out, int N, int rmask) {
    int n = blockIdx.x * blockDim.x + threadIdx.x;
    if (n >= N) return;

    // 16 independent coalesced float2 loads (SoA) — all issued up front.
    float xe[32];
    #pragma unroll
    for (int l = 0; l < NLVL; ++l) {
        float2 v = xe_ws[(size_t)l * N + n];
        xe[2*l+0] = v.x;
        xe[2*l+1] = v.y;
    }

    // density MLP: 32 -> 64 (relu) -> 16 (sigmoid)
    float h[64];
    dense<32, 64, 0>(w1, b1, xe, h);
    float cin[40];
    {
        float dens[16];
        dense<64, 16, 1>(w2, b2, h, dens);
        #pragma unroll
        for (int i = 0; i < 16; ++i) cin[i] = dens[i];
    }
    float dens0 = cin[0];

    // direction features (precomputed per ray, coalesced: consecutive n -> consecutive ray)
    int ray = n & rmask;
    const float4* der = reinterpret_cast<const float4*>(De + 24 * ray);
    #pragma unroll
    for (int i = 0; i < 6; ++i) {
        float4 v = der[i];
        cin[16 + 4*i + 0] = v.x;
        cin[16 + 4*i + 1] = v.y;
        cin[16 + 4*i + 2] = v.z;
        cin[16 + 4*i + 3] = v.w;
    }

    // colour MLP: 40 -> 64 (relu) -> [64 (relu) -> 3 (sigmoid)] fused head
    float c1[64];
    dense<40, 64, 0>(cw1, cb1, cin, c1);
    float ca0 = cb3[0], ca1 = cb3[1], ca2 = cb3[2];
    #pragma unroll
    for (int o = 0; o < 64; ++o) {
        float acc = cb2[o];
        const float4* wr = reinterpret_cast<const float4*>(cw2 + o * 64);
        #pragma unroll
        for (int i = 0; i < 16; ++i) {
            float4 w = wr[i];
            acc = fmaf(w.x, c1[4*i+0], acc);
            acc = fmaf(w.y, c1[4*i+1], acc);
            acc = fmaf(w.z, c1[4*i+2], acc);
            acc = fmaf(w.w, c1[4*i+3], acc);
        }
        float c2o = fmaxf(acc, 0.0f);
        ca0 = fmaf(cw3[0 * 64 + o], c2o, ca0);
        ca1 = fmaf(cw3[1 * 64 + o], c2o, ca1);
        ca2 = fmaf(cw3[2 * 64 + o], c2o, ca2);
    }

    out[n] = dens0;
    float* oc = out + N;
    __builtin_nontemporal_store(sigmoid_act(ca0), &oc[3*n+0]);
    __builtin_nontemporal_store(sigmoid_act(ca1), &oc[3*n+1]);
    __builtin_nontemporal_store(sigmoid_act(ca2), &oc[3*n+2]);
}

// ---------------------------------------------------------------------------
// Fallback: fully fused single-kernel path (used only if ws is too small).
// ---------------------------------------------------------------------------
template<bool USE_WS>
__global__ __launch_bounds__(256)
void ngp_fused(const float* __restrict__ X,
               const float* __restrict__ D,
               const float* __restrict__ tables,
               const float* __restrict__ w1, const float* __restrict__ b1,
               const float* __restrict__ w2, const float* __restrict__ b2,
               const float* __restrict__ cw1, const float* __restrict__ cb1,
               const float* __restrict__ cw2, const float* __restrict__ cb2,
               const float* __restrict__ cw3, const float* __restrict__ cb3,
               const float* __restrict__ De,
               float* __restrict__ out, int N, int R, int rmask, ResList res) {
    int n = blockIdx.x * blockDim.x + threadIdx.x;
    if (n >= N) return;
    float x = X[3*n+0], y = X[3*n+1], z = X[3*n+2];

    float xe[32];
    #pragma unroll
    for (int l = 0; l < NLVL; ++l) {
        float rs = res.r[l];
        float sx = x * rs, sy = y * rs, sz = z * rs;
        float px = floorf(sx), py = floorf(sy), pz = floorf(sz);
        float fx = sx - px, fy = sy - py, fz = sz - pz;
        unsigned cx = (unsigned)(int)px;
        unsigned cy = (unsigned)(int)py;
        unsigned cz = (unsigned)(int)pz;
        unsigned hx[2] = { cx,          cx + 1u };
        unsigned hy[2] = { cy * PRIME1, cy * PRIME1 + PRIME1 };
        unsigned hz[2] = { cz * PRIME2, cz * PRIME2 + PRIME2 };
        float wxv[2] = { 1.0f - fx, fx };
        float wyv[2] = { 1.0f - fy, fy };
        float wzv[2] = { 1.0f - fz, fz };
        const float2* tl = reinterpret_cast<const float2*>(tables) + (size_t)l * TSZ;
        float f0 = 0.0f, f1 = 0.0f;
        #pragma unroll
        for (int i = 0; i < 2; ++i)
            #pragma unroll
            for (int j = 0; j < 2; ++j)
                #pragma unroll
                for (int k = 0; k < 2; ++k) {
                    unsigned idx = (hx[i] ^ hy[j] ^ hz[k]) & TMSK;
                    float2 f = tl[idx];
                    float w = wxv[i] * wyv[j] * wzv[k];
                    f0 = fmaf(w, f.x, f0);
                    f1 = fmaf(w, f.y, f1);
                }
        xe[2*l+0] = f0;
        xe[2*l+1] = f1;
    }

    float h[64];
    dense<32, 64, 0>(w1, b1, xe, h);
    float cin[40];
    {
        float dens[16];
        dense<64, 16, 1>(w2, b2, h, dens);
        #pragma unroll
        for (int i = 0; i < 16; ++i) cin[i] = dens[i];
    }
    float dens0 = cin[0];

    int ray = rmask ? (n & rmask) : (n % R);
    if (USE_WS) {
        const float4* der = reinterpret_cast<const float4*>(De + 24 * ray);
        #pragma unroll
        for (int i = 0; i < 6; ++i) {
            float4 v = der[i];
            cin[16 + 4*i + 0] = v.x;
            cin[16 + 4*i + 1] = v.y;
            cin[16 + 4*i + 2] = v.z;
            cin[16 + 4*i + 3] = v.w;
        }
    } else {
        float d0 = D[3*ray+0], d1 = D[3*ray+1], d2 = D[3*ray+2];
        #pragma unroll
        for (int i = 0; i < 4; ++i) {
            float s = (float)((double)(1 << i) * M_PI);
            cin[16 + 6*i + 0] = sinf(s * d0);
            cin[16 + 6*i + 1] = sinf(s * d1);
            cin[16 + 6*i + 2] = sinf(s * d2);
            cin[16 + 6*i + 3] = cosf(s * d0);
            cin[16 + 6*i + 4] = cosf(s * d1);
            cin[16 + 6*i + 5] = cosf(s * d2);
        }
    }

    float c1[64];
    dense<40, 64, 0>(cw1, cb1, cin, c1);
    float ca0 = cb3[0], ca1 = cb3[1], ca2 = cb3[2];
    #pragma unroll
    for (int o = 0; o < 64; ++o) {
        float acc = cb2[o];
        const float4* wr = reinterpret_cast<const float4*>(cw2 + o * 64);
        #pragma unroll
        for (int i = 0; i < 16; ++i) {
            float4 w = wr[i];
            acc = fmaf(w.x, c1[4*i+0], acc);
            acc = fmaf(w.y, c1[4*i+1], acc);
            acc = fmaf(w.z, c1[4*i+2], acc);
            acc = fmaf(w.w, c1[4*i+3], acc);
        }
        float c2o = fmaxf(acc, 0.0f);
        ca0 = fmaf(cw3[0 * 64 + o], c2o, ca0);
        ca1 = fmaf(cw3[1 * 64 + o], c2o, ca1);
        ca2 = fmaf(cw3[2 * 64 + o], c2o, ca2);
    }

    out[n] = dens0;
    float* oc = out + N;
    __builtin_nontemporal_store(sigmoid_act(ca0), &oc[3*n+0]);
    __builtin_nontemporal_store(sigmoid_act(ca1), &oc[3*n+1]);
    __builtin_nontemporal_store(sigmoid_act(ca2), &oc[3*n+2]);
}

extern "C" void kernel_launch(void* const* d_in, const int* in_sizes, int n_in,
                              void* d_out, int out_size, void* d_ws, size_t ws_size,
                              hipStream_t stream) {
    const float* X      = (const float*)d_in[0];
    const float* D      = (const float*)d_in[1];
    // d_in[2] is M (device scalar) — not readable without sync; derive from sizes.
    const float* tables = (const float*)d_in[3];
    const float* w1  = (const float*)d_in[4];
    const float* b1  = (const float*)d_in[5];
    const float* w2  = (const float*)d_in[6];
    const float* b2  = (const float*)d_in[7];
    const float* cw1 = (const float*)d_in[8];
    const float* cb1 = (const float*)d_in[9];
    const float* cw2 = (const float*)d_in[10];
    const float* cb2 = (const float*)d_in[11];
    const float* cw3 = (const float*)d_in[12];
    const float* cb3 = (const float*)d_in[13];

    int N = in_sizes[0] / 3;   // 1,048,576 sample points
    int R = in_sizes[1] / 3;   // 32,768 rays
    int rmask = ((R & (R - 1)) == 0) ? (R - 1) : 0;  // pow2 fast path for n % R
    float* out = (float*)d_out;

    // Resolutions: must match numpy's double-precision floor(16 * (32^(1/15))^l).
    ResList res;
    double B = pow(32.0, 1.0 / 15.0);
    for (int l = 0; l < NLVL; ++l) res.r[l] = (float)floor(16.0 * pow(B, (double)l));

    size_t de_bytes = (size_t)R * 24 * sizeof(float);
    size_t de_al    = (de_bytes + 255) & ~(size_t)255;
    size_t xe_bytes = (size_t)N * 32 * sizeof(float);   // 128 MB @ N=1M
    int pblocks = (N + 255) / 256;

    if (ws_size >= de_al + xe_bytes && rmask) {
        // --- split path: dir encode -> per-level hash encode -> MLP chain ---
        float* De = (float*)d_ws;
        unsigned long long* xe_ws = (unsigned long long*)((char*)d_ws + de_al);
        dir_encode_kernel<<<(R + 255) / 256, 256, 0, stream>>>(D, De, R);
        hash_encode_kernel<<<pblocks * NLVL, 256, 0, stream>>>(X, tables, xe_ws, N, res);
        mlp_kernel<<<pblocks, 256, 0, stream>>>((const float2*)xe_ws, De,
            w1, b1, w2, b2, cw1, cb1, cw2, cb2, cw3, cb3, out, N, rmask);
    } else if (ws_size >= de_bytes) {
        float* De = (float*)d_ws;
        dir_encode_kernel<<<(R + 255) / 256, 256, 0, stream>>>(D, De, R);
        ngp_fused<true><<<pblocks, 256, 0, stream>>>(X, D, tables, w1, b1, w2, b2,
            cw1, cb1, cw2, cb2, cw3, cb3, De, out, N, R, rmask, res);
    } else {
        ngp_fused<false><<<pblocks, 256, 0, stream>>>(X, D, tables, w1, b1, w2, b2,
            cw1, cb1, cw2, cb2, cw3, cb3, nullptr, out, N, R, rmask, res);
    }
}